// Round 14
// baseline (282.441 us; speedup 1.0000x reference)
//
#include <hip/hip_runtime.h>
#include <hip/hip_fp16.h>
#include <math.h>

#define NEG_SLOPE 0.2f
#define NBMAX 256
#define CHUNK 4096
#define DCAP 16384
#define NREP 32

typedef _Float16 half8 __attribute__((ext_vector_type(8)));
typedef float f32x4 __attribute__((ext_vector_type(4)));

__device__ __forceinline__ float lrelu(float x) { return x > 0.f ? x : NEG_SLOPE * x; }

__device__ __forceinline__ float h2f(unsigned short u) {
    __half h = *(__half*)&u;
    return __half2float(h);
}

// ---------------- CSR build: 2-level bucket counting sort ----------------
__global__ __launch_bounds__(256) void k_hist(const int* __restrict__ ei, int* __restrict__ bCntR,
                                              int E, int n) {
    __shared__ int lh[NBMAX];
    for (int i = threadIdx.x; i < NBMAX; i += 256) lh[i] = 0;
    __syncthreads();
    int E2 = E + n;
    for (int e = blockIdx.x * 256 + threadIdx.x; e < E2; e += gridDim.x * 256) {
        int d = (e < E) ? ei[E + e] : (e - E);
        atomicAdd(&lh[d >> 8], 1);
    }
    __syncthreads();
    int rep = blockIdx.x & (NREP - 1);
    for (int i = threadIdx.x; i < NBMAX; i += 256)
        if (lh[i]) atomicAdd(&bCntR[rep * NBMAX + i], lh[i]);
}

__global__ __launch_bounds__(256) void k_bscan(const int* __restrict__ bCntR, int* __restrict__ bOff,
                                               int* __restrict__ bFill, int* __restrict__ rowptr,
                                               int n, int E2) {
    int NB = (n + 255) >> 8;
    int tid = threadIdx.x, lane = tid & 63, wid = tid >> 6;
    int v0 = 0, v1 = 0, v2 = 0, v3 = 0;
    #pragma unroll
    for (int r = 0; r < NREP; r += 4) {
        v0 += bCntR[(r + 0) * NBMAX + tid];
        v1 += bCntR[(r + 1) * NBMAX + tid];
        v2 += bCntR[(r + 2) * NBMAX + tid];
        v3 += bCntR[(r + 3) * NBMAX + tid];
    }
    int v = (tid < NB) ? (v0 + v1 + v2 + v3) : 0;
    int s = v;
    #pragma unroll
    for (int off = 1; off < 64; off <<= 1) {
        int t = __shfl_up(s, off);
        if (lane >= off) s += t;
    }
    __shared__ int ws[4];
    if (lane == 63) ws[wid] = s;
    __syncthreads();
    if (tid == 0) {
        int c = 0;
        #pragma unroll
        for (int i = 0; i < 4; ++i) { int t = ws[i]; ws[i] = c; c += t; }
    }
    __syncthreads();
    s += ws[wid];
    int excl = s - v;
    if (tid < NB) { bOff[tid] = excl; bFill[tid] = excl; }
    if (tid == NB - 1) bOff[NB] = excl + v;
    if (tid == 0) rowptr[n] = E2;
}

__global__ __launch_bounds__(256) void k_partition(const int* __restrict__ ei, int* __restrict__ bFill,
                                                   unsigned int* __restrict__ staging, int E, int n) {
    __shared__ int lh[NBMAX];
    __shared__ int lbase[NBMAX];
    int E2 = E + n;
    int beg = blockIdx.x * CHUNK;
    int end = min(beg + CHUNK, E2);
    for (int i = threadIdx.x; i < NBMAX; i += 256) lh[i] = 0;
    __syncthreads();
    for (int e = beg + threadIdx.x; e < end; e += 256) {
        int d = (e < E) ? ei[E + e] : (e - E);
        atomicAdd(&lh[d >> 8], 1);
    }
    __syncthreads();
    for (int i = threadIdx.x; i < NBMAX; i += 256) {
        int c = lh[i];
        lbase[i] = c ? atomicAdd(&bFill[i], c) : 0;
        lh[i] = 0;
    }
    __syncthreads();
    for (int e = beg + threadIdx.x; e < end; e += 256) {
        int s, d;
        if (e < E) { s = ei[e]; d = ei[E + e]; } else { s = d = e - E; }
        int b = d >> 8;
        int r = atomicAdd(&lh[b], 1);
        staging[lbase[b] + r] = ((unsigned)s << 8) | (unsigned)(d & 255);
    }
}

__global__ __launch_bounds__(512) void k_emit(const unsigned int* __restrict__ staging,
                                              const int* __restrict__ bOff, int* __restrict__ rowptr,
                                              int* __restrict__ csr, int n) {
    __shared__ int lcnt[NBMAX];
    __shared__ int lscan[NBMAX];
    __shared__ int ws[4];
    __shared__ int sorted[DCAP];  // 64 KB
    int b = blockIdx.x;
    int gbase = b << 8;
    int beg = bOff[b], end = bOff[b + 1], m = end - beg;
    int tid = threadIdx.x, lane = tid & 63, wid = tid >> 6;

    if (tid < 256) lcnt[tid] = 0;
    __syncthreads();
    for (int j = tid; j < m; j += 512) atomicAdd(&lcnt[staging[beg + j] & 255], 1);
    __syncthreads();
    int v = 0, s = 0;
    if (tid < 256) {
        v = lcnt[tid];
        s = v;
        #pragma unroll
        for (int off = 1; off < 64; off <<= 1) {
            int t = __shfl_up(s, off);
            if (lane >= off) s += t;
        }
        if (lane == 63) ws[wid] = s;
    }
    __syncthreads();
    if (tid == 0) {
        int c = 0;
        #pragma unroll
        for (int i = 0; i < 4; ++i) { int t = ws[i]; ws[i] = c; c += t; }
    }
    __syncthreads();
    if (tid < 256) {
        int excl = s + ws[wid] - v;
        lscan[tid] = excl;
        lcnt[tid] = 0;
        if (gbase + tid < n) rowptr[gbase + tid] = beg + excl;
    }
    __syncthreads();

    if (m <= DCAP) {
        for (int j = tid; j < m; j += 512) {
            unsigned e = staging[beg + j];
            int ld = e & 255;
            int src = e >> 8;
            int r = atomicAdd(&lcnt[ld], 1);
            sorted[lscan[ld] + r] = src;
        }
        __syncthreads();
        for (int j = tid; j < m; j += 512) csr[beg + j] = sorted[j];
    } else {
        for (int j = tid; j < m; j += 512) {
            unsigned e = staging[beg + j];
            int ld = e & 255;
            int src = e >> 8;
            int r = atomicAdd(&lcnt[ld], 1);
            csr[beg + lscan[ld] + r] = src;
        }
    }
}

// ---------------- W prep: fp32 [k][n] -> f16 swizzled [n][k], both layers ----------------
__global__ __launch_bounds__(256) void k_wprep(const float* __restrict__ W1, const float* __restrict__ W2,
                                               unsigned short* __restrict__ Wsw) {
    int flat = blockIdx.x * 256 + threadIdx.x;  // 0..32767
    int layer = flat >> 14;
    int idx = flat & 16383;
    int k = idx >> 7, nn = idx & 127;
    const float* W = layer ? W2 : W1;
    _Float16 h = (_Float16)W[idx];
    int byte = nn * 256 + k * 2;
    byte ^= (nn & 7) << 4;
    *(unsigned short*)((char*)(Wsw + (size_t)layer * 16384) + byte) = *(unsigned short*)&h;
}

// ---------------- MFMA GEMM: H(f16) = relu(X*scale+shift) @ W, fused es/ed ----------------
// W arrives pre-swizzled f16: staging is a straight coalesced 32KB copy.
// Blocks 0..31 zero the 32-replica BN accumulator for the following bn_stats.
__global__ __launch_bounds__(256) void k_gemm_mfma(
    const float* __restrict__ X, const unsigned short* __restrict__ Wsw,
    unsigned short* __restrict__ Hout,
    const float* __restrict__ scale, const float* __restrict__ shift,
    const float* __restrict__ as_f, const float* __restrict__ ad_f,
    float* __restrict__ es, float* __restrict__ ed,
    float* __restrict__ bnzero, int n) {
    __shared__ _Float16 WT[128 * 128];  // 32 KB, swizzled [n][k]
    int tid = threadIdx.x;
    if (blockIdx.x < NREP) bnzero[blockIdx.x * 256 + tid] = 0.f;

    const uint4* Wg = (const uint4*)Wsw;  // 2048 uint4
    uint4* WT4 = (uint4*)WT;
    #pragma unroll
    for (int t = 0; t < 8; ++t) WT4[tid + t * 256] = Wg[tid + t * 256];
    __syncthreads();

    int wid = tid >> 6, lane = tid & 63;
    int l15 = lane & 15, lg = lane >> 4;
    int row0 = blockIdx.x * 64 + wid * 16;
    int myrow = row0 + l15;
    bool rok = myrow < n;

    f32x4 acc[8];
    #pragma unroll
    for (int i = 0; i < 8; ++i) acc[i] = (f32x4){0.f, 0.f, 0.f, 0.f};

    #pragma unroll
    for (int ks = 0; ks < 4; ++ks) {
        int kb = ks * 32 + lg * 8;
        half8 a;
        #pragma unroll
        for (int j = 0; j < 8; ++j) a[j] = (_Float16)0.f;
        if (rok) {
            float4 x0 = *(const float4*)(X + (size_t)myrow * 128 + kb);
            float4 x1 = *(const float4*)(X + (size_t)myrow * 128 + kb + 4);
            if (scale) {
                float4 sc0 = *(const float4*)&scale[kb], sh0 = *(const float4*)&shift[kb];
                float4 sc1 = *(const float4*)&scale[kb + 4], sh1 = *(const float4*)&shift[kb + 4];
                x0.x = fmaxf(x0.x * sc0.x + sh0.x, 0.f);
                x0.y = fmaxf(x0.y * sc0.y + sh0.y, 0.f);
                x0.z = fmaxf(x0.z * sc0.z + sh0.z, 0.f);
                x0.w = fmaxf(x0.w * sc0.w + sh0.w, 0.f);
                x1.x = fmaxf(x1.x * sc1.x + sh1.x, 0.f);
                x1.y = fmaxf(x1.y * sc1.y + sh1.y, 0.f);
                x1.z = fmaxf(x1.z * sc1.z + sh1.z, 0.f);
                x1.w = fmaxf(x1.w * sc1.w + sh1.w, 0.f);
            }
            a[0] = (_Float16)x0.x; a[1] = (_Float16)x0.y;
            a[2] = (_Float16)x0.z; a[3] = (_Float16)x0.w;
            a[4] = (_Float16)x1.x; a[5] = (_Float16)x1.y;
            a[6] = (_Float16)x1.z; a[7] = (_Float16)x1.w;
        }
        #pragma unroll
        for (int nt = 0; nt < 8; ++nt) {
            int nn = nt * 16 + l15;
            int byte = nn * 256 + kb * 2;
            byte ^= (nn & 7) << 4;
            half8 b = *(const half8*)((const char*)WT + byte);
            acc[nt] = __builtin_amdgcn_mfma_f32_16x16x32_f16(a, b, acc[nt], 0, 0, 0);
        }
    }

    #pragma unroll
    for (int nt = 0; nt < 8; ++nt) {
        #pragma unroll
        for (int r = 0; r < 4; ++r) {
            int rr = row0 + lg * 4 + r;
            if (rr < n) {
                _Float16 hv = (_Float16)acc[nt][r];
                Hout[(size_t)rr * 128 + nt * 16 + l15] = *(unsigned short*)&hv;
            }
        }
    }

    float asv[8], adv[8];
    #pragma unroll
    for (int nt = 0; nt < 8; ++nt) {
        asv[nt] = as_f[nt * 16 + l15];
        adv[nt] = ad_f[nt * 16 + l15];
    }
    float ps[4][4], pd[4][4];
    #pragma unroll
    for (int h = 0; h < 4; ++h)
        #pragma unroll
        for (int r = 0; r < 4; ++r) { ps[h][r] = 0.f; pd[h][r] = 0.f; }
    #pragma unroll
    for (int nt = 0; nt < 8; ++nt) {
        int h = nt >> 1;
        #pragma unroll
        for (int r = 0; r < 4; ++r) {
            ps[h][r] += acc[nt][r] * asv[nt];
            pd[h][r] += acc[nt][r] * adv[nt];
        }
    }
    #pragma unroll
    for (int off = 1; off <= 8; off <<= 1) {
        #pragma unroll
        for (int h = 0; h < 4; ++h)
            #pragma unroll
            for (int r = 0; r < 4; ++r) {
                ps[h][r] += __shfl_xor(ps[h][r], off);
                pd[h][r] += __shfl_xor(pd[h][r], off);
            }
    }
    if (l15 == 0) {
        #pragma unroll
        for (int r = 0; r < 4; ++r) {
            int rr = row0 + lg * 4 + r;
            if (rr < n) {
                #pragma unroll
                for (int h = 0; h < 4; ++h) {
                    es[(size_t)rr * 4 + h] = ps[h][r];
                    ed[(size_t)rr * 4 + h] = pd[h][r];
                }
            }
        }
    }
}

// ---------------- per-node GAT: node-per-wave, 16-lane x 16B gather ----------------
__global__ __launch_bounds__(256) void k_node_gat(
    const unsigned short* __restrict__ Hf, const float* __restrict__ es, const float* __restrict__ ed,
    const int* __restrict__ ptr, const int* __restrict__ csr,
    const float* __restrict__ bias, float* __restrict__ out, int n) {
    int nd = blockIdx.x * 4 + (threadIdx.x >> 6);
    if (nd >= n) return;
    int lane = threadIdx.x & 63;
    int cg = lane & 15;    // channel group (8 ch = 16 B)
    int slot = lane >> 4;  // 0..3
    int hh = cg >> 2;      // head
    int beg = ptr[nd], deg = ptr[nd + 1] - beg;

    float edn = ed[(unsigned)nd * 4u + hh];
    const uint4* H4 = (const uint4*)Hf;  // row stride = 16 uint4
    const int* cs = csr + beg;

    float a0 = 0.f, a1 = 0.f, a2 = 0.f, a3 = 0.f, a4 = 0.f, a5 = 0.f, a6 = 0.f, a7 = 0.f;
    float den = 0.f;

    int i = slot;
    for (; i + 4 < deg; i += 8) {
        int s0 = cs[i];
        int s1 = cs[i + 4];
        float e0 = es[(unsigned)s0 * 4u + hh];
        float e1 = es[(unsigned)s1 * 4u + hh];
        uint4 p0 = H4[(unsigned)s0 * 16u + cg];
        uint4 p1 = H4[(unsigned)s1 * 16u + cg];
        float w0 = __expf(lrelu(e0 + edn) - 16.f);
        float w1 = __expf(lrelu(e1 + edn) - 16.f);
        den += w0 + w1;
        a0 += w0 * h2f(p0.x & 0xffff) + w1 * h2f(p1.x & 0xffff);
        a1 += w0 * h2f(p0.x >> 16)    + w1 * h2f(p1.x >> 16);
        a2 += w0 * h2f(p0.y & 0xffff) + w1 * h2f(p1.y & 0xffff);
        a3 += w0 * h2f(p0.y >> 16)    + w1 * h2f(p1.y >> 16);
        a4 += w0 * h2f(p0.z & 0xffff) + w1 * h2f(p1.z & 0xffff);
        a5 += w0 * h2f(p0.z >> 16)    + w1 * h2f(p1.z >> 16);
        a6 += w0 * h2f(p0.w & 0xffff) + w1 * h2f(p1.w & 0xffff);
        a7 += w0 * h2f(p0.w >> 16)    + w1 * h2f(p1.w >> 16);
    }
    if (i < deg) {
        int s0 = cs[i];
        float e0 = es[(unsigned)s0 * 4u + hh];
        uint4 p0 = H4[(unsigned)s0 * 16u + cg];
        float w0 = __expf(lrelu(e0 + edn) - 16.f);
        den += w0;
        a0 += w0 * h2f(p0.x & 0xffff);
        a1 += w0 * h2f(p0.x >> 16);
        a2 += w0 * h2f(p0.y & 0xffff);
        a3 += w0 * h2f(p0.y >> 16);
        a4 += w0 * h2f(p0.z & 0xffff);
        a5 += w0 * h2f(p0.z >> 16);
        a6 += w0 * h2f(p0.w & 0xffff);
        a7 += w0 * h2f(p0.w >> 16);
    }

    #pragma unroll
    for (int off = 32; off >= 16; off >>= 1) {
        a0 += __shfl_xor(a0, off); a1 += __shfl_xor(a1, off);
        a2 += __shfl_xor(a2, off); a3 += __shfl_xor(a3, off);
        a4 += __shfl_xor(a4, off); a5 += __shfl_xor(a5, off);
        a6 += __shfl_xor(a6, off); a7 += __shfl_xor(a7, off);
        den += __shfl_xor(den, off);
    }

    if (lane < 16) {
        float inv = 1.f / (den + 1e-16f);
        const float4* bv4 = (const float4*)&bias[cg * 8];
        float4 b0 = bv4[0], b1 = bv4[1];
        float4 o0 = make_float4(a0 * inv + b0.x, a1 * inv + b0.y, a2 * inv + b0.z, a3 * inv + b0.w);
        float4 o1 = make_float4(a4 * inv + b1.x, a5 * inv + b1.y, a6 * inv + b1.z, a7 * inv + b1.w);
        float4* o4 = (float4*)&out[(size_t)nd * 128 + cg * 8];
        o4[0] = o0;
        o4[1] = o1;
    }
}

// ---------------- batch norm stats: 32-replica atomics + last-block finalize ----------------
__global__ __launch_bounds__(256) void k_bn_stats(const float* __restrict__ G, float* __restrict__ bnG,
                                                  int* __restrict__ cnt,
                                                  const float* __restrict__ g, const float* __restrict__ be,
                                                  float* __restrict__ scale, float* __restrict__ shift,
                                                  int n) {
    int tid = threadIdx.x;
    int cg = tid & 31;
    int rsub = tid >> 5;
    const float4* G4 = (const float4*)G;
    float4 s = make_float4(0.f, 0.f, 0.f, 0.f);
    float4 q = make_float4(0.f, 0.f, 0.f, 0.f);
    for (int r = blockIdx.x * 8 + rsub; r < n; r += gridDim.x * 8) {
        float4 v = G4[(size_t)r * 32 + cg];
        s.x += v.x; s.y += v.y; s.z += v.z; s.w += v.w;
        q.x += v.x * v.x; q.y += v.y * v.y; q.z += v.z * v.z; q.w += v.w * v.w;
    }
    s.x += __shfl_xor(s.x, 32); s.y += __shfl_xor(s.y, 32);
    s.z += __shfl_xor(s.z, 32); s.w += __shfl_xor(s.w, 32);
    q.x += __shfl_xor(q.x, 32); q.y += __shfl_xor(q.y, 32);
    q.z += __shfl_xor(q.z, 32); q.w += __shfl_xor(q.w, 32);
    __shared__ float4 redS[4][32];
    __shared__ float4 redQ[4][32];
    __shared__ int isLast;
    int wid = tid >> 6, lane = tid & 63;
    if (lane < 32) { redS[wid][cg] = s; redQ[wid][cg] = q; }
    __syncthreads();
    if (tid < 32) {
        float4 S = redS[0][tid], Q = redQ[0][tid];
        #pragma unroll
        for (int w = 1; w < 4; ++w) {
            float4 a = redS[w][tid], b = redQ[w][tid];
            S.x += a.x; S.y += a.y; S.z += a.z; S.w += a.w;
            Q.x += b.x; Q.y += b.y; Q.z += b.z; Q.w += b.w;
        }
        float* dst = bnG + (blockIdx.x & (NREP - 1)) * 256;
        int c = tid * 4;
        atomicAdd(&dst[c + 0], S.x); atomicAdd(&dst[c + 1], S.y);
        atomicAdd(&dst[c + 2], S.z); atomicAdd(&dst[c + 3], S.w);
        atomicAdd(&dst[128 + c + 0], Q.x); atomicAdd(&dst[128 + c + 1], Q.y);
        atomicAdd(&dst[128 + c + 2], Q.z); atomicAdd(&dst[128 + c + 3], Q.w);
    }
    __syncthreads();
    if (tid == 0) {
        __threadfence();
        int old = atomicAdd(cnt, 1);
        isLast = (old == (int)gridDim.x - 1) ? 1 : 0;
    }
    __syncthreads();
    if (isLast) {
        __threadfence();
        if (tid < 128) {
            const volatile float* vb = bnG;
            float s0 = 0.f, s1 = 0.f, s2 = 0.f, s3 = 0.f;
            float q0 = 0.f, q1 = 0.f, q2 = 0.f, q3 = 0.f;
            #pragma unroll
            for (int r = 0; r < NREP; r += 4) {
                s0 += vb[(r + 0) * 256 + tid];
                s1 += vb[(r + 1) * 256 + tid];
                s2 += vb[(r + 2) * 256 + tid];
                s3 += vb[(r + 3) * 256 + tid];
                q0 += vb[(r + 0) * 256 + 128 + tid];
                q1 += vb[(r + 1) * 256 + 128 + tid];
                q2 += vb[(r + 2) * 256 + 128 + tid];
                q3 += vb[(r + 3) * 256 + 128 + tid];
            }
            float ss = (s0 + s1) + (s2 + s3);
            float qq = (q0 + q1) + (q2 + q3);
            float mean = ss / (float)n;
            float var = qq / (float)n - mean * mean;
            float sc = g[tid] * rsqrtf(var + 1e-5f);
            scale[tid] = sc;
            shift[tid] = be[tid] - mean * sc;
        }
    }
}

// ---------------- layer 3 (BN+ReLU fused into dot) ----------------
__global__ __launch_bounds__(256) void k_dot3(const float* __restrict__ F, const float* __restrict__ W3,
                                              const float* __restrict__ scale, const float* __restrict__ shift,
                                              float* __restrict__ h3, int n) {
    int wid = threadIdx.x >> 6, lane = threadIdx.x & 63;
    int nd = blockIdx.x * 4 + wid;
    if (nd >= n) return;
    const float* row = F + (size_t)nd * 128;
    float v0 = fmaxf(row[lane] * scale[lane] + shift[lane], 0.f);
    float v1 = fmaxf(row[lane + 64] * scale[lane + 64] + shift[lane + 64], 0.f);
    float v = v0 * W3[lane] + v1 * W3[lane + 64];
    #pragma unroll
    for (int off = 32; off > 0; off >>= 1) v += __shfl_xor(v, off);
    if (lane == 0) h3[nd] = v;
}

// ---------------- layer-3 GAT: wave-per-node, 4 nodes/block ----------------
__global__ __launch_bounds__(256) void k_gat3(const float* __restrict__ h3, const float* __restrict__ a3s,
                                              const float* __restrict__ a3d, const float* __restrict__ b3,
                                              const int* __restrict__ ptr, const int* __restrict__ csr,
                                              float* __restrict__ out, int n) {
    int nd = blockIdx.x * 4 + (threadIdx.x >> 6);
    if (nd >= n) return;
    int lane = threadIdx.x & 63;
    int beg = ptr[nd], deg = ptr[nd + 1] - beg;
    float As = a3s[0], Ad = a3d[0], B = b3[0];
    float hd = h3[nd] * Ad;
    float den = 0.f, num = 0.f;
    for (int i = lane; i < deg; i += 64) {
        float hs = h3[csr[beg + i]];
        float a = lrelu(hs * As + hd);
        float ex = __expf(a - 16.f);
        den += ex;
        num += ex * hs;
    }
    #pragma unroll
    for (int off = 32; off > 0; off >>= 1) {
        den += __shfl_xor(den, off);
        num += __shfl_xor(num, off);
    }
    if (lane == 0) out[nd] = fmaxf(num / (den + 1e-16f) + B, 0.f);
}

// ---------------- launch ----------------
extern "C" void kernel_launch(void* const* d_in, const int* in_sizes, int n_in,
                              void* d_out, int out_size, void* d_ws, size_t ws_size,
                              hipStream_t stream) {
    const int N_ = in_sizes[0] / 128;
    const int E_ = in_sizes[1] / 2;
    const int E2 = E_ + N_;
    const int NB = (N_ + 255) >> 8;

    const float* x = (const float*)d_in[0];
    const int* ei = (const int*)d_in[1];
    const float* W1 = (const float*)d_in[2];
    const float* a1s = (const float*)d_in[3];
    const float* a1d = (const float*)d_in[4];
    const float* b1 = (const float*)d_in[5];
    const float* g1 = (const float*)d_in[6];
    const float* be1 = (const float*)d_in[7];
    const float* W2 = (const float*)d_in[8];
    const float* a2s = (const float*)d_in[9];
    const float* a2d = (const float*)d_in[10];
    const float* b2 = (const float*)d_in[11];
    const float* g2 = (const float*)d_in[12];
    const float* be2 = (const float*)d_in[13];
    const float* W3 = (const float*)d_in[14];
    const float* a3s = (const float*)d_in[15];
    const float* a3d = (const float*)d_in[16];
    const float* b3 = (const float*)d_in[17];
    float* out = (float*)d_out;

    char* p = (char*)d_ws;
    auto alloc = [&](size_t bytes) {
        void* r = (void*)p;
        p += (bytes + 255) & ~(size_t)255;
        return r;
    };
    int* bCntR = (int*)alloc((size_t)NREP * NBMAX * 4);
    int* lbc = (int*)alloc(8);  // 2 last-block counters, zeroed with bCntR memset
    int* bOff = (int*)alloc((size_t)(NBMAX + 1) * 4);
    int* bFill = (int*)alloc((size_t)NBMAX * 4);
    int* rowptr = (int*)alloc((size_t)(N_ + 1) * 4);
    unsigned int* staging = (unsigned int*)alloc((size_t)E2 * 4);
    int* csr = (int*)alloc((size_t)E2 * 4);
    unsigned short* Hb = (unsigned short*)alloc((size_t)N_ * 128 * 2);
    float* G = (float*)alloc((size_t)N_ * 128 * 4);
    float* es = (float*)alloc((size_t)N_ * 4 * 4);
    float* ed = (float*)alloc((size_t)N_ * 4 * 4);
    float* h3 = (float*)alloc((size_t)N_ * 4);
    unsigned short* Wsw = (unsigned short*)alloc((size_t)2 * 16384 * 2);  // 2 layers, swizzled f16
    float* bnG = (float*)alloc((size_t)NREP * 256 * 4);
    float* bnss = (float*)alloc(256 * 4);  // scale(128) + shift(128)

    // CSR build (memset also zeroes the two last-block counters right after bCntR)
    hipMemsetAsync(bCntR, 0, (size_t)NREP * NBMAX * 4 + 256, stream);
    k_wprep<<<128, 256, 0, stream>>>(W1, W2, Wsw);
    k_hist<<<512, 256, 0, stream>>>(ei, bCntR, E_, N_);
    k_bscan<<<1, 256, 0, stream>>>(bCntR, bOff, bFill, rowptr, N_, E2);
    k_partition<<<(E2 + CHUNK - 1) / CHUNK, 256, 0, stream>>>(ei, bFill, staging, E_, N_);
    k_emit<<<NB, 512, 0, stream>>>(staging, bOff, rowptr, csr, N_);

    int gemmB = (N_ + 63) / 64;
    int gatB = (N_ + 3) / 4;

    // ----- layer 1 -----
    k_gemm_mfma<<<gemmB, 256, 0, stream>>>(x, Wsw, Hb, nullptr, nullptr, a1s, a1d, es, ed, bnG, N_);
    k_node_gat<<<gatB, 256, 0, stream>>>(Hb, es, ed, rowptr, csr, b1, G, N_);
    k_bn_stats<<<512, 256, 0, stream>>>(G, bnG, lbc, g1, be1, bnss, bnss + 128, N_);

    // ----- layer 2 (BN1+ReLU fused into GEMM X-load; GEMM re-zeros bnG) -----
    k_gemm_mfma<<<gemmB, 256, 0, stream>>>(G, Wsw + 16384, Hb, bnss, bnss + 128, a2s, a2d, es, ed, bnG, N_);
    k_node_gat<<<gatB, 256, 0, stream>>>(Hb, es, ed, rowptr, csr, b2, G, N_);
    k_bn_stats<<<512, 256, 0, stream>>>(G, bnG, lbc + 1, g2, be2, bnss, bnss + 128, N_);

    // ----- layer 3 (BN2+ReLU fused into dot) -----
    k_dot3<<<(N_ + 3) / 4, 256, 0, stream>>>(G, W3, bnss, bnss + 128, h3, N_);
    k_gat3<<<gatB, 256, 0, stream>>>(h3, a3s, a3d, b3, rowptr, csr, out, N_);
}

// Round 15
// 242.991 us; speedup vs baseline: 1.1624x; 1.1624x over previous
//
#include <hip/hip_runtime.h>
#include <hip/hip_fp16.h>
#include <math.h>

#define NEG_SLOPE 0.2f
#define NBMAX 256
#define CHUNK 4096
#define DCAP 16384
#define NREP 32

typedef _Float16 half8 __attribute__((ext_vector_type(8)));
typedef float f32x4 __attribute__((ext_vector_type(4)));

__device__ __forceinline__ float lrelu(float x) { return x > 0.f ? x : NEG_SLOPE * x; }

__device__ __forceinline__ float h2f(unsigned short u) {
    __half h = *(__half*)&u;
    return __half2float(h);
}

// ---------------- CSR build: 2-level bucket counting sort ----------------
__global__ __launch_bounds__(256) void k_hist(const int* __restrict__ ei, int* __restrict__ bCntR,
                                              int E, int n) {
    __shared__ int lh[NBMAX];
    for (int i = threadIdx.x; i < NBMAX; i += 256) lh[i] = 0;
    __syncthreads();
    int E2 = E + n;
    for (int e = blockIdx.x * 256 + threadIdx.x; e < E2; e += gridDim.x * 256) {
        int d = (e < E) ? ei[E + e] : (e - E);
        atomicAdd(&lh[d >> 8], 1);
    }
    __syncthreads();
    int rep = blockIdx.x & (NREP - 1);
    for (int i = threadIdx.x; i < NBMAX; i += 256)
        if (lh[i]) atomicAdd(&bCntR[rep * NBMAX + i], lh[i]);
}

__global__ __launch_bounds__(256) void k_bscan(const int* __restrict__ bCntR, int* __restrict__ bOff,
                                               int* __restrict__ bFill, int* __restrict__ rowptr,
                                               int n, int E2) {
    int NB = (n + 255) >> 8;
    int tid = threadIdx.x, lane = tid & 63, wid = tid >> 6;
    int v0 = 0, v1 = 0, v2 = 0, v3 = 0;
    #pragma unroll
    for (int r = 0; r < NREP; r += 4) {
        v0 += bCntR[(r + 0) * NBMAX + tid];
        v1 += bCntR[(r + 1) * NBMAX + tid];
        v2 += bCntR[(r + 2) * NBMAX + tid];
        v3 += bCntR[(r + 3) * NBMAX + tid];
    }
    int v = (tid < NB) ? (v0 + v1 + v2 + v3) : 0;
    int s = v;
    #pragma unroll
    for (int off = 1; off < 64; off <<= 1) {
        int t = __shfl_up(s, off);
        if (lane >= off) s += t;
    }
    __shared__ int ws[4];
    if (lane == 63) ws[wid] = s;
    __syncthreads();
    if (tid == 0) {
        int c = 0;
        #pragma unroll
        for (int i = 0; i < 4; ++i) { int t = ws[i]; ws[i] = c; c += t; }
    }
    __syncthreads();
    s += ws[wid];
    int excl = s - v;
    if (tid < NB) { bOff[tid] = excl; bFill[tid] = excl; }
    if (tid == NB - 1) bOff[NB] = excl + v;
    if (tid == 0) rowptr[n] = E2;
}

__global__ __launch_bounds__(256) void k_partition(const int* __restrict__ ei, int* __restrict__ bFill,
                                                   unsigned int* __restrict__ staging, int E, int n) {
    __shared__ int lh[NBMAX];
    __shared__ int lbase[NBMAX];
    int E2 = E + n;
    int beg = blockIdx.x * CHUNK;
    int end = min(beg + CHUNK, E2);
    for (int i = threadIdx.x; i < NBMAX; i += 256) lh[i] = 0;
    __syncthreads();
    for (int e = beg + threadIdx.x; e < end; e += 256) {
        int d = (e < E) ? ei[E + e] : (e - E);
        atomicAdd(&lh[d >> 8], 1);
    }
    __syncthreads();
    for (int i = threadIdx.x; i < NBMAX; i += 256) {
        int c = lh[i];
        lbase[i] = c ? atomicAdd(&bFill[i], c) : 0;
        lh[i] = 0;
    }
    __syncthreads();
    for (int e = beg + threadIdx.x; e < end; e += 256) {
        int s, d;
        if (e < E) { s = ei[e]; d = ei[E + e]; } else { s = d = e - E; }
        int b = d >> 8;
        int r = atomicAdd(&lh[b], 1);
        staging[lbase[b] + r] = ((unsigned)s << 8) | (unsigned)(d & 255);
    }
}

__global__ __launch_bounds__(512) void k_emit(const unsigned int* __restrict__ staging,
                                              const int* __restrict__ bOff, int* __restrict__ rowptr,
                                              int* __restrict__ csr, int n) {
    __shared__ int lcnt[NBMAX];
    __shared__ int lscan[NBMAX];
    __shared__ int ws[4];
    __shared__ int sorted[DCAP];  // 64 KB
    int b = blockIdx.x;
    int gbase = b << 8;
    int beg = bOff[b], end = bOff[b + 1], m = end - beg;
    int tid = threadIdx.x, lane = tid & 63, wid = tid >> 6;

    if (tid < 256) lcnt[tid] = 0;
    __syncthreads();
    for (int j = tid; j < m; j += 512) atomicAdd(&lcnt[staging[beg + j] & 255], 1);
    __syncthreads();
    int v = 0, s = 0;
    if (tid < 256) {
        v = lcnt[tid];
        s = v;
        #pragma unroll
        for (int off = 1; off < 64; off <<= 1) {
            int t = __shfl_up(s, off);
            if (lane >= off) s += t;
        }
        if (lane == 63) ws[wid] = s;
    }
    __syncthreads();
    if (tid == 0) {
        int c = 0;
        #pragma unroll
        for (int i = 0; i < 4; ++i) { int t = ws[i]; ws[i] = c; c += t; }
    }
    __syncthreads();
    if (tid < 256) {
        int excl = s + ws[wid] - v;
        lscan[tid] = excl;
        lcnt[tid] = 0;
        if (gbase + tid < n) rowptr[gbase + tid] = beg + excl;
    }
    __syncthreads();

    if (m <= DCAP) {
        for (int j = tid; j < m; j += 512) {
            unsigned e = staging[beg + j];
            int ld = e & 255;
            int src = e >> 8;
            int r = atomicAdd(&lcnt[ld], 1);
            sorted[lscan[ld] + r] = src;
        }
        __syncthreads();
        for (int j = tid; j < m; j += 512) csr[beg + j] = sorted[j];
    } else {
        for (int j = tid; j < m; j += 512) {
            unsigned e = staging[beg + j];
            int ld = e & 255;
            int src = e >> 8;
            int r = atomicAdd(&lcnt[ld], 1);
            csr[beg + lscan[ld] + r] = src;
        }
    }
}

// ---------------- W prep: fp32 [k][n] -> f16 swizzled [n][k], both layers ----------------
__global__ __launch_bounds__(256) void k_wprep(const float* __restrict__ W1, const float* __restrict__ W2,
                                               unsigned short* __restrict__ Wsw) {
    int flat = blockIdx.x * 256 + threadIdx.x;  // 0..32767
    int layer = flat >> 14;
    int idx = flat & 16383;
    int k = idx >> 7, nn = idx & 127;
    const float* W = layer ? W2 : W1;
    _Float16 h = (_Float16)W[idx];
    int byte = nn * 256 + k * 2;
    byte ^= (nn & 7) << 4;
    *(unsigned short*)((char*)(Wsw + (size_t)layer * 16384) + byte) = *(unsigned short*)&h;
}

// ---------------- MFMA GEMM: H(f16) = relu(X*scale+shift) @ W, fused es/ed ----------------
// W arrives pre-swizzled f16: staging is a straight coalesced 32KB copy.
// Blocks 0..31 zero the 32-replica BN accumulator for the following bn_stats.
__global__ __launch_bounds__(256) void k_gemm_mfma(
    const float* __restrict__ X, const unsigned short* __restrict__ Wsw,
    unsigned short* __restrict__ Hout,
    const float* __restrict__ scale, const float* __restrict__ shift,
    const float* __restrict__ as_f, const float* __restrict__ ad_f,
    float* __restrict__ es, float* __restrict__ ed,
    float* __restrict__ bnzero, int n) {
    __shared__ _Float16 WT[128 * 128];  // 32 KB, swizzled [n][k]
    int tid = threadIdx.x;
    if (blockIdx.x < NREP) bnzero[blockIdx.x * 256 + tid] = 0.f;

    const uint4* Wg = (const uint4*)Wsw;  // 2048 uint4
    uint4* WT4 = (uint4*)WT;
    #pragma unroll
    for (int t = 0; t < 8; ++t) WT4[tid + t * 256] = Wg[tid + t * 256];
    __syncthreads();

    int wid = tid >> 6, lane = tid & 63;
    int l15 = lane & 15, lg = lane >> 4;
    int row0 = blockIdx.x * 64 + wid * 16;
    int myrow = row0 + l15;
    bool rok = myrow < n;

    f32x4 acc[8];
    #pragma unroll
    for (int i = 0; i < 8; ++i) acc[i] = (f32x4){0.f, 0.f, 0.f, 0.f};

    #pragma unroll
    for (int ks = 0; ks < 4; ++ks) {
        int kb = ks * 32 + lg * 8;
        half8 a;
        #pragma unroll
        for (int j = 0; j < 8; ++j) a[j] = (_Float16)0.f;
        if (rok) {
            float4 x0 = *(const float4*)(X + (size_t)myrow * 128 + kb);
            float4 x1 = *(const float4*)(X + (size_t)myrow * 128 + kb + 4);
            if (scale) {
                float4 sc0 = *(const float4*)&scale[kb], sh0 = *(const float4*)&shift[kb];
                float4 sc1 = *(const float4*)&scale[kb + 4], sh1 = *(const float4*)&shift[kb + 4];
                x0.x = fmaxf(x0.x * sc0.x + sh0.x, 0.f);
                x0.y = fmaxf(x0.y * sc0.y + sh0.y, 0.f);
                x0.z = fmaxf(x0.z * sc0.z + sh0.z, 0.f);
                x0.w = fmaxf(x0.w * sc0.w + sh0.w, 0.f);
                x1.x = fmaxf(x1.x * sc1.x + sh1.x, 0.f);
                x1.y = fmaxf(x1.y * sc1.y + sh1.y, 0.f);
                x1.z = fmaxf(x1.z * sc1.z + sh1.z, 0.f);
                x1.w = fmaxf(x1.w * sc1.w + sh1.w, 0.f);
            }
            a[0] = (_Float16)x0.x; a[1] = (_Float16)x0.y;
            a[2] = (_Float16)x0.z; a[3] = (_Float16)x0.w;
            a[4] = (_Float16)x1.x; a[5] = (_Float16)x1.y;
            a[6] = (_Float16)x1.z; a[7] = (_Float16)x1.w;
        }
        #pragma unroll
        for (int nt = 0; nt < 8; ++nt) {
            int nn = nt * 16 + l15;
            int byte = nn * 256 + kb * 2;
            byte ^= (nn & 7) << 4;
            half8 b = *(const half8*)((const char*)WT + byte);
            acc[nt] = __builtin_amdgcn_mfma_f32_16x16x32_f16(a, b, acc[nt], 0, 0, 0);
        }
    }

    #pragma unroll
    for (int nt = 0; nt < 8; ++nt) {
        #pragma unroll
        for (int r = 0; r < 4; ++r) {
            int rr = row0 + lg * 4 + r;
            if (rr < n) {
                _Float16 hv = (_Float16)acc[nt][r];
                Hout[(size_t)rr * 128 + nt * 16 + l15] = *(unsigned short*)&hv;
            }
        }
    }

    float asv[8], adv[8];
    #pragma unroll
    for (int nt = 0; nt < 8; ++nt) {
        asv[nt] = as_f[nt * 16 + l15];
        adv[nt] = ad_f[nt * 16 + l15];
    }
    float ps[4][4], pd[4][4];
    #pragma unroll
    for (int h = 0; h < 4; ++h)
        #pragma unroll
        for (int r = 0; r < 4; ++r) { ps[h][r] = 0.f; pd[h][r] = 0.f; }
    #pragma unroll
    for (int nt = 0; nt < 8; ++nt) {
        int h = nt >> 1;
        #pragma unroll
        for (int r = 0; r < 4; ++r) {
            ps[h][r] += acc[nt][r] * asv[nt];
            pd[h][r] += acc[nt][r] * adv[nt];
        }
    }
    #pragma unroll
    for (int off = 1; off <= 8; off <<= 1) {
        #pragma unroll
        for (int h = 0; h < 4; ++h)
            #pragma unroll
            for (int r = 0; r < 4; ++r) {
                ps[h][r] += __shfl_xor(ps[h][r], off);
                pd[h][r] += __shfl_xor(pd[h][r], off);
            }
    }
    if (l15 == 0) {
        #pragma unroll
        for (int r = 0; r < 4; ++r) {
            int rr = row0 + lg * 4 + r;
            if (rr < n) {
                #pragma unroll
                for (int h = 0; h < 4; ++h) {
                    es[(size_t)rr * 4 + h] = ps[h][r];
                    ed[(size_t)rr * 4 + h] = pd[h][r];
                }
            }
        }
    }
}

// ---------------- per-node GAT: node-per-wave, 16-lane x 16B gather ----------------
__global__ __launch_bounds__(256) void k_node_gat(
    const unsigned short* __restrict__ Hf, const float* __restrict__ es, const float* __restrict__ ed,
    const int* __restrict__ ptr, const int* __restrict__ csr,
    const float* __restrict__ bias, float* __restrict__ out, int n) {
    int nd = blockIdx.x * 4 + (threadIdx.x >> 6);
    if (nd >= n) return;
    int lane = threadIdx.x & 63;
    int cg = lane & 15;    // channel group (8 ch = 16 B)
    int slot = lane >> 4;  // 0..3
    int hh = cg >> 2;      // head
    int beg = ptr[nd], deg = ptr[nd + 1] - beg;

    float edn = ed[(unsigned)nd * 4u + hh];
    const uint4* H4 = (const uint4*)Hf;  // row stride = 16 uint4
    const int* cs = csr + beg;

    float a0 = 0.f, a1 = 0.f, a2 = 0.f, a3 = 0.f, a4 = 0.f, a5 = 0.f, a6 = 0.f, a7 = 0.f;
    float den = 0.f;

    int i = slot;
    for (; i + 4 < deg; i += 8) {
        int s0 = cs[i];
        int s1 = cs[i + 4];
        float e0 = es[(unsigned)s0 * 4u + hh];
        float e1 = es[(unsigned)s1 * 4u + hh];
        uint4 p0 = H4[(unsigned)s0 * 16u + cg];
        uint4 p1 = H4[(unsigned)s1 * 16u + cg];
        float w0 = __expf(lrelu(e0 + edn) - 16.f);
        float w1 = __expf(lrelu(e1 + edn) - 16.f);
        den += w0 + w1;
        a0 += w0 * h2f(p0.x & 0xffff) + w1 * h2f(p1.x & 0xffff);
        a1 += w0 * h2f(p0.x >> 16)    + w1 * h2f(p1.x >> 16);
        a2 += w0 * h2f(p0.y & 0xffff) + w1 * h2f(p1.y & 0xffff);
        a3 += w0 * h2f(p0.y >> 16)    + w1 * h2f(p1.y >> 16);
        a4 += w0 * h2f(p0.z & 0xffff) + w1 * h2f(p1.z & 0xffff);
        a5 += w0 * h2f(p0.z >> 16)    + w1 * h2f(p1.z >> 16);
        a6 += w0 * h2f(p0.w & 0xffff) + w1 * h2f(p1.w & 0xffff);
        a7 += w0 * h2f(p0.w >> 16)    + w1 * h2f(p1.w >> 16);
    }
    if (i < deg) {
        int s0 = cs[i];
        float e0 = es[(unsigned)s0 * 4u + hh];
        uint4 p0 = H4[(unsigned)s0 * 16u + cg];
        float w0 = __expf(lrelu(e0 + edn) - 16.f);
        den += w0;
        a0 += w0 * h2f(p0.x & 0xffff);
        a1 += w0 * h2f(p0.x >> 16);
        a2 += w0 * h2f(p0.y & 0xffff);
        a3 += w0 * h2f(p0.y >> 16);
        a4 += w0 * h2f(p0.z & 0xffff);
        a5 += w0 * h2f(p0.z >> 16);
        a6 += w0 * h2f(p0.w & 0xffff);
        a7 += w0 * h2f(p0.w >> 16);
    }

    #pragma unroll
    for (int off = 32; off >= 16; off >>= 1) {
        a0 += __shfl_xor(a0, off); a1 += __shfl_xor(a1, off);
        a2 += __shfl_xor(a2, off); a3 += __shfl_xor(a3, off);
        a4 += __shfl_xor(a4, off); a5 += __shfl_xor(a5, off);
        a6 += __shfl_xor(a6, off); a7 += __shfl_xor(a7, off);
        den += __shfl_xor(den, off);
    }

    if (lane < 16) {
        float inv = 1.f / (den + 1e-16f);
        const float4* bv4 = (const float4*)&bias[cg * 8];
        float4 b0 = bv4[0], b1 = bv4[1];
        float4 o0 = make_float4(a0 * inv + b0.x, a1 * inv + b0.y, a2 * inv + b0.z, a3 * inv + b0.w);
        float4 o1 = make_float4(a4 * inv + b1.x, a5 * inv + b1.y, a6 * inv + b1.z, a7 * inv + b1.w);
        float4* o4 = (float4*)&out[(size_t)nd * 128 + cg * 8];
        o4[0] = o0;
        o4[1] = o1;
    }
}

// ---------------- batch norm stats: block-reduced, 32-replica atomic finish ----------------
__global__ __launch_bounds__(256) void k_bn_stats(const float* __restrict__ G, float* __restrict__ bnG,
                                                  int n) {
    int tid = threadIdx.x;
    int cg = tid & 31;
    int rsub = tid >> 5;
    const float4* G4 = (const float4*)G;
    float4 s = make_float4(0.f, 0.f, 0.f, 0.f);
    float4 q = make_float4(0.f, 0.f, 0.f, 0.f);
    for (int r = blockIdx.x * 8 + rsub; r < n; r += gridDim.x * 8) {
        float4 v = G4[(size_t)r * 32 + cg];
        s.x += v.x; s.y += v.y; s.z += v.z; s.w += v.w;
        q.x += v.x * v.x; q.y += v.y * v.y; q.z += v.z * v.z; q.w += v.w * v.w;
    }
    s.x += __shfl_xor(s.x, 32); s.y += __shfl_xor(s.y, 32);
    s.z += __shfl_xor(s.z, 32); s.w += __shfl_xor(s.w, 32);
    q.x += __shfl_xor(q.x, 32); q.y += __shfl_xor(q.y, 32);
    q.z += __shfl_xor(q.z, 32); q.w += __shfl_xor(q.w, 32);
    __shared__ float4 redS[4][32];
    __shared__ float4 redQ[4][32];
    int wid = tid >> 6, lane = tid & 63;
    if (lane < 32) { redS[wid][cg] = s; redQ[wid][cg] = q; }
    __syncthreads();
    if (tid < 32) {
        float4 S = redS[0][tid], Q = redQ[0][tid];
        #pragma unroll
        for (int w = 1; w < 4; ++w) {
            float4 a = redS[w][tid], b = redQ[w][tid];
            S.x += a.x; S.y += a.y; S.z += a.z; S.w += a.w;
            Q.x += b.x; Q.y += b.y; Q.z += b.z; Q.w += b.w;
        }
        float* dst = bnG + (blockIdx.x & (NREP - 1)) * 256;
        int c = tid * 4;
        atomicAdd(&dst[c + 0], S.x); atomicAdd(&dst[c + 1], S.y);
        atomicAdd(&dst[c + 2], S.z); atomicAdd(&dst[c + 3], S.w);
        atomicAdd(&dst[128 + c + 0], Q.x); atomicAdd(&dst[128 + c + 1], Q.y);
        atomicAdd(&dst[128 + c + 2], Q.z); atomicAdd(&dst[128 + c + 3], Q.w);
    }
}

// ---------------- BN finalize: reduce 32 replicas (4-way unrolled) ----------------
__global__ void k_bn_finalize(const float* __restrict__ bnG,
                              const float* __restrict__ g, const float* __restrict__ be,
                              float* __restrict__ scale, float* __restrict__ shift, int n) {
    int c = threadIdx.x;  // 128
    float s0 = 0.f, s1 = 0.f, s2 = 0.f, s3 = 0.f;
    float q0 = 0.f, q1 = 0.f, q2 = 0.f, q3 = 0.f;
    #pragma unroll
    for (int r = 0; r < NREP; r += 4) {
        s0 += bnG[(r + 0) * 256 + c];
        s1 += bnG[(r + 1) * 256 + c];
        s2 += bnG[(r + 2) * 256 + c];
        s3 += bnG[(r + 3) * 256 + c];
        q0 += bnG[(r + 0) * 256 + 128 + c];
        q1 += bnG[(r + 1) * 256 + 128 + c];
        q2 += bnG[(r + 2) * 256 + 128 + c];
        q3 += bnG[(r + 3) * 256 + 128 + c];
    }
    float s = (s0 + s1) + (s2 + s3);
    float q = (q0 + q1) + (q2 + q3);
    float mean = s / (float)n;
    float var = q / (float)n - mean * mean;
    float sc = g[c] * rsqrtf(var + 1e-5f);
    scale[c] = sc;
    shift[c] = be[c] - mean * sc;
}

// ---------------- layer 3 (BN+ReLU fused into dot) ----------------
__global__ __launch_bounds__(256) void k_dot3(const float* __restrict__ F, const float* __restrict__ W3,
                                              const float* __restrict__ scale, const float* __restrict__ shift,
                                              float* __restrict__ h3, int n) {
    int wid = threadIdx.x >> 6, lane = threadIdx.x & 63;
    int nd = blockIdx.x * 4 + wid;
    if (nd >= n) return;
    const float* row = F + (size_t)nd * 128;
    float v0 = fmaxf(row[lane] * scale[lane] + shift[lane], 0.f);
    float v1 = fmaxf(row[lane + 64] * scale[lane + 64] + shift[lane + 64], 0.f);
    float v = v0 * W3[lane] + v1 * W3[lane + 64];
    #pragma unroll
    for (int off = 32; off > 0; off >>= 1) v += __shfl_xor(v, off);
    if (lane == 0) h3[nd] = v;
}

// ---------------- layer-3 GAT: wave-per-node, 4 nodes/block ----------------
__global__ __launch_bounds__(256) void k_gat3(const float* __restrict__ h3, const float* __restrict__ a3s,
                                              const float* __restrict__ a3d, const float* __restrict__ b3,
                                              const int* __restrict__ ptr, const int* __restrict__ csr,
                                              float* __restrict__ out, int n) {
    int nd = blockIdx.x * 4 + (threadIdx.x >> 6);
    if (nd >= n) return;
    int lane = threadIdx.x & 63;
    int beg = ptr[nd], deg = ptr[nd + 1] - beg;
    float As = a3s[0], Ad = a3d[0], B = b3[0];
    float hd = h3[nd] * Ad;
    float den = 0.f, num = 0.f;
    for (int i = lane; i < deg; i += 64) {
        float hs = h3[csr[beg + i]];
        float a = lrelu(hs * As + hd);
        float ex = __expf(a - 16.f);
        den += ex;
        num += ex * hs;
    }
    #pragma unroll
    for (int off = 32; off > 0; off >>= 1) {
        den += __shfl_xor(den, off);
        num += __shfl_xor(num, off);
    }
    if (lane == 0) out[nd] = fmaxf(num / (den + 1e-16f) + B, 0.f);
}

// ---------------- launch ----------------
extern "C" void kernel_launch(void* const* d_in, const int* in_sizes, int n_in,
                              void* d_out, int out_size, void* d_ws, size_t ws_size,
                              hipStream_t stream) {
    const int N_ = in_sizes[0] / 128;
    const int E_ = in_sizes[1] / 2;
    const int E2 = E_ + N_;
    const int NB = (N_ + 255) >> 8;

    const float* x = (const float*)d_in[0];
    const int* ei = (const int*)d_in[1];
    const float* W1 = (const float*)d_in[2];
    const float* a1s = (const float*)d_in[3];
    const float* a1d = (const float*)d_in[4];
    const float* b1 = (const float*)d_in[5];
    const float* g1 = (const float*)d_in[6];
    const float* be1 = (const float*)d_in[7];
    const float* W2 = (const float*)d_in[8];
    const float* a2s = (const float*)d_in[9];
    const float* a2d = (const float*)d_in[10];
    const float* b2 = (const float*)d_in[11];
    const float* g2 = (const float*)d_in[12];
    const float* be2 = (const float*)d_in[13];
    const float* W3 = (const float*)d_in[14];
    const float* a3s = (const float*)d_in[15];
    const float* a3d = (const float*)d_in[16];
    const float* b3 = (const float*)d_in[17];
    float* out = (float*)d_out;

    char* p = (char*)d_ws;
    auto alloc = [&](size_t bytes) {
        void* r = (void*)p;
        p += (bytes + 255) & ~(size_t)255;
        return r;
    };
    int* bCntR = (int*)alloc((size_t)NREP * NBMAX * 4);
    int* bOff = (int*)alloc((size_t)(NBMAX + 1) * 4);
    int* bFill = (int*)alloc((size_t)NBMAX * 4);
    int* rowptr = (int*)alloc((size_t)(N_ + 1) * 4);
    unsigned int* staging = (unsigned int*)alloc((size_t)E2 * 4);
    int* csr = (int*)alloc((size_t)E2 * 4);
    unsigned short* Hb = (unsigned short*)alloc((size_t)N_ * 128 * 2);
    float* G = (float*)alloc((size_t)N_ * 128 * 4);
    float* es = (float*)alloc((size_t)N_ * 4 * 4);
    float* ed = (float*)alloc((size_t)N_ * 4 * 4);
    float* h3 = (float*)alloc((size_t)N_ * 4);
    unsigned short* Wsw = (unsigned short*)alloc((size_t)2 * 16384 * 2);  // 2 layers, swizzled f16
    float* bnG = (float*)alloc((size_t)NREP * 256 * 4);
    float* bnss = (float*)alloc(256 * 4);  // scale(128) + shift(128)

    // CSR build + W prep
    hipMemsetAsync(bCntR, 0, (size_t)NREP * NBMAX * 4, stream);
    k_wprep<<<128, 256, 0, stream>>>(W1, W2, Wsw);
    k_hist<<<512, 256, 0, stream>>>(ei, bCntR, E_, N_);
    k_bscan<<<1, 256, 0, stream>>>(bCntR, bOff, bFill, rowptr, N_, E2);
    k_partition<<<(E2 + CHUNK - 1) / CHUNK, 256, 0, stream>>>(ei, bFill, staging, E_, N_);
    k_emit<<<NB, 512, 0, stream>>>(staging, bOff, rowptr, csr, N_);

    int gemmB = (N_ + 63) / 64;
    int gatB = (N_ + 3) / 4;

    // ----- layer 1 -----
    k_gemm_mfma<<<gemmB, 256, 0, stream>>>(x, Wsw, Hb, nullptr, nullptr, a1s, a1d, es, ed, bnG, N_);
    k_node_gat<<<gatB, 256, 0, stream>>>(Hb, es, ed, rowptr, csr, b1, G, N_);
    k_bn_stats<<<512, 256, 0, stream>>>(G, bnG, N_);
    k_bn_finalize<<<1, 128, 0, stream>>>(bnG, g1, be1, bnss, bnss + 128, N_);

    // ----- layer 2 (BN1+ReLU fused into GEMM X-load; GEMM re-zeros bnG) -----
    k_gemm_mfma<<<gemmB, 256, 0, stream>>>(G, Wsw + 16384, Hb, bnss, bnss + 128, a2s, a2d, es, ed, bnG, N_);
    k_node_gat<<<gatB, 256, 0, stream>>>(Hb, es, ed, rowptr, csr, b2, G, N_);
    k_bn_stats<<<512, 256, 0, stream>>>(G, bnG, N_);
    k_bn_finalize<<<1, 128, 0, stream>>>(bnG, g2, be2, bnss, bnss + 128, N_);

    // ----- layer 3 (BN2+ReLU fused into dot) -----
    k_dot3<<<(N_ + 3) / 4, 256, 0, stream>>>(G, W3, bnss, bnss + 128, h3, N_);
    k_gat3<<<gatB, 256, 0, stream>>>(h3, a3s, a3d, b3, rowptr, csr, out, N_);
}